// Round 7
// baseline (113.145 us; speedup 1.0000x reference)
//
#include <hip/hip_runtime.h>

// Problem constants (match reference)
#define N_VOX      200000
#define N_CLUST    2000
#define CLUST_SIZE 100
#define N_EDGE     32000
#define N_FEAT     16

// Output: 6.4M points x 16 fp32 feats = 409.6 MB -> write-BW-bound.
//
// R6: factor the compute. Column 3 of every input row is overwritten with
// the edge id e, so
//     y[p,f] = ReLU( h[c,v,f] + e * W[3,f] )
//     h[c,v,f] = sum_{i in {0,1,2,4}} data[clusts[c,v], i] * W[i,f]
// Pass 1 precomputes h[N_CLUST*CLUST_SIZE*N_FEAT] (12.8 MB, d_ws, CACHED
// stores - we want it L2/L3 resident). Pass 2 (the 409.6 MB writer) then has
// NO random gather: per point it reads one contiguous f32x4 of h (4 lanes of
// a point read consecutive 16 B chunks; a wave reads a contiguous 1 KiB run
// inside a cluster block) + one broadcast edge_index read. 2-hop chain,
// ~zero HBM read traffic (h has 32x avg reuse, L3-resident).
// Stores stay NONTEMPORAL (don't evict h from L2).

#define TOTAL_QUADS (N_EDGE * 2 * CLUST_SIZE * 4)   // 25,600,000
#define HALF_QUADS  (TOTAL_QUADS / 2)               // 12,800,000
#define BLOCK       256
#define GRID_MAIN   (HALF_QUADS / BLOCK)            // 50,000

#define PRE_THREADS (N_CLUST * CLUST_SIZE * 4)      // 800,000
#define GRID_PRE    (PRE_THREADS / BLOCK)           // 3,125

typedef float f32x4 __attribute__((ext_vector_type(4)));

// ---------- pass 1: h[cv, f] = sum_{i!=3} data[clusts[cv], i] * W[i, f] ----
__global__ __launch_bounds__(BLOCK) void precompute_kernel(
    const float* __restrict__ data,        // [N_VOX, 5]
    const int*   __restrict__ clusts,      // [N_CLUST * CLUST_SIZE]
    const float* __restrict__ W,           // [5, 16]
    float*       __restrict__ h)           // [N_CLUST*CLUST_SIZE, 16]
{
    const unsigned t  = blockIdx.x * BLOCK + threadIdx.x;  // 0 .. 800K-1
    const unsigned cv = t >> 2;          // cluster-voxel slot 0 .. 200K-1
    const unsigned fb = t & 3u;          // feature quad

    const int vox = clusts[cv];          // 4 lanes same addr (broadcast)

    const f32x4* __restrict__ Wv = reinterpret_cast<const f32x4*>(W);
    const f32x4 w0 = Wv[0 * 4 + fb];
    const f32x4 w1 = Wv[1 * 4 + fb];
    const f32x4 w2 = Wv[2 * 4 + fb];
    const f32x4 w4 = Wv[4 * 4 + fb];

    const float* dr = data + (size_t)vox * 5;
    const float x0 = dr[0], x1 = dr[1], x2 = dr[2], x4 = dr[4];

    f32x4 g;
#pragma unroll
    for (int q = 0; q < 4; ++q)
        g[q] = fmaf(x0, w0[q], fmaf(x1, w1[q], fmaf(x2, w2[q], x4 * w4[q])));

    // cached store: h must stay in L2/L3 for pass 2
    *reinterpret_cast<f32x4*>(h + (size_t)cv * N_FEAT + fb * 4u) = g;
}

// ---------- pass 2: y[p] = ReLU(h[c,v] + e*W3), dense nt stores ----------
__global__ __launch_bounds__(BLOCK) void edge_enc_kernel(
    const float* __restrict__ h,           // [N_CLUST*CLUST_SIZE, 16]
    const int*   __restrict__ edge_index,  // [2, N_EDGE]
    const float* __restrict__ W,           // [5, 16]
    float*       __restrict__ out)         // [N_EDGE*200, 16]
{
    const unsigned t = blockIdx.x * BLOCK + threadIdx.x;    // 0 .. 12.8M-1

    // Both quads share fb since HALF_QUADS % 4 == 0.
    const unsigned fb    = t & 3u;
    const unsigned fbase = fb * 4u;

    // W row 3 sub-column (broadcast vector load, no LDS, no barrier)
    const f32x4 w3 = reinterpret_cast<const f32x4*>(W)[3 * 4 + fb];

    // ---- two independent chains ----
    const unsigned p0 = t >> 2;
    const unsigned p1 = (t + (unsigned)HALF_QUADS) >> 2;

    const unsigned e0 = p0 / 200u;                 // magic-mul
    const unsigned e1 = p1 / 200u;
    const unsigned j0 = p0 - e0 * 200u;
    const unsigned j1 = p1 - e1 * 200u;
    const unsigned s0 = (j0 >= 100u) ? 1u : 0u;
    const unsigned s1 = (j1 >= 100u) ? 1u : 0u;
    const unsigned v0 = j0 - s0 * 100u;
    const unsigned v1 = j1 - s1 * 100u;

    const int c0 = edge_index[s0 * N_EDGE + e0];   // broadcast over 200 pts
    const int c1 = edge_index[s1 * N_EDGE + e1];

    // contiguous, aligned 16 B reads; consecutive lanes -> consecutive 16 B
    const f32x4 h0 = *reinterpret_cast<const f32x4*>(
        h + ((size_t)c0 * CLUST_SIZE + v0) * N_FEAT + fbase);
    const f32x4 h1 = *reinterpret_cast<const f32x4*>(
        h + ((size_t)c1 * CLUST_SIZE + v1) * N_FEAT + fbase);

    const float fe0 = (float)e0;
    const float fe1 = (float)e1;

    f32x4 r0, r1;
#pragma unroll
    for (int q = 0; q < 4; ++q) {
        r0[q] = fmaxf(fmaf(fe0, w3[q], h0[q]), 0.0f);
        r1[q] = fmaxf(fmaf(fe1, w3[q], h1[q]), 0.0f);
    }

    __builtin_nontemporal_store(r0,
        reinterpret_cast<f32x4*>(out + (size_t)p0 * N_FEAT + fbase));
    __builtin_nontemporal_store(r1,
        reinterpret_cast<f32x4*>(out + (size_t)p1 * N_FEAT + fbase));
}

// ---------- fallback (R2 structure, direct 3-hop gather) ----------
__global__ __launch_bounds__(BLOCK) void edge_enc_direct_kernel(
    const float* __restrict__ data,
    const int*   __restrict__ clusts,
    const int*   __restrict__ edge_index,
    const float* __restrict__ W,
    float*       __restrict__ out)
{
    __shared__ float Ws[5 * N_FEAT];
    if (threadIdx.x < 5 * N_FEAT) Ws[threadIdx.x] = W[threadIdx.x];
    __syncthreads();

    const unsigned t = blockIdx.x * BLOCK + threadIdx.x;
    const unsigned fb    = t & 3u;
    const unsigned fbase = fb * 4u;

    float w0[4], w1[4], w2[4], w3[4], w4[4];
#pragma unroll
    for (int q = 0; q < 4; ++q) {
        w0[q] = Ws[0 * N_FEAT + fbase + q];
        w1[q] = Ws[1 * N_FEAT + fbase + q];
        w2[q] = Ws[2 * N_FEAT + fbase + q];
        w3[q] = Ws[3 * N_FEAT + fbase + q];
        w4[q] = Ws[4 * N_FEAT + fbase + q];
    }

    const unsigned p0 = t >> 2;
    const unsigned p1 = (t + (unsigned)HALF_QUADS) >> 2;
    const unsigned e0 = p0 / 200u, e1 = p1 / 200u;
    const unsigned j0 = p0 - e0 * 200u, j1 = p1 - e1 * 200u;
    const unsigned s0 = (j0 >= 100u) ? 1u : 0u, s1 = (j1 >= 100u) ? 1u : 0u;
    const unsigned v0 = j0 - s0 * 100u, v1 = j1 - s1 * 100u;

    const int c0 = edge_index[s0 * N_EDGE + e0];
    const int c1 = edge_index[s1 * N_EDGE + e1];
    const int vox0 = clusts[c0 * CLUST_SIZE + (int)v0];
    const int vox1 = clusts[c1 * CLUST_SIZE + (int)v1];

    const float* dr0 = data + (size_t)vox0 * 5;
    const float* dr1 = data + (size_t)vox1 * 5;
    const float a0 = dr0[0], a1 = dr0[1], a2 = dr0[2], a4 = dr0[4];
    const float b0 = dr1[0], b1 = dr1[1], b2 = dr1[2], b4 = dr1[4];
    const float a3 = (float)e0, b3 = (float)e1;

    f32x4 ova, ovb;
#pragma unroll
    for (int q = 0; q < 4; ++q) {
        float va = fmaf(a0, w0[q], fmaf(a1, w1[q], fmaf(a2, w2[q],
                   fmaf(a3, w3[q], a4 * w4[q]))));
        float vb = fmaf(b0, w0[q], fmaf(b1, w1[q], fmaf(b2, w2[q],
                   fmaf(b3, w3[q], b4 * w4[q]))));
        ova[q] = fmaxf(va, 0.0f);
        ovb[q] = fmaxf(vb, 0.0f);
    }
    __builtin_nontemporal_store(ova,
        reinterpret_cast<f32x4*>(out + (size_t)p0 * N_FEAT + fbase));
    __builtin_nontemporal_store(ovb,
        reinterpret_cast<f32x4*>(out + (size_t)p1 * N_FEAT + fbase));
}

extern "C" void kernel_launch(void* const* d_in, const int* in_sizes, int n_in,
                              void* d_out, int out_size, void* d_ws, size_t ws_size,
                              hipStream_t stream) {
    const float* data       = (const float*)d_in[0];
    const int*   clusts     = (const int*)d_in[1];
    const int*   edge_index = (const int*)d_in[2];
    const float* W          = (const float*)d_in[3];
    float*       out        = (float*)d_out;

    const size_t h_bytes = (size_t)N_CLUST * CLUST_SIZE * N_FEAT * sizeof(float); // 12.8 MB
    if (ws_size >= h_bytes) {
        float* h = (float*)d_ws;
        precompute_kernel<<<GRID_PRE, BLOCK, 0, stream>>>(data, clusts, W, h);
        edge_enc_kernel<<<GRID_MAIN, BLOCK, 0, stream>>>(h, edge_index, W, out);
    } else {
        edge_enc_direct_kernel<<<GRID_MAIN, BLOCK, 0, stream>>>(
            data, clusts, edge_index, W, out);
    }
}

// Round 8
// 78.765 us; speedup vs baseline: 1.4365x; 1.4365x over previous
//
#include <hip/hip_runtime.h>

// Problem constants (match reference)
#define N_VOX      200000
#define N_CLUST    2000
#define CLUST_SIZE 100
#define N_EDGE     32000
#define N_FEAT     16

// Output: 6.4M points x 16 fp32 feats = 409.6 MB -> write-BW-bound.
//
// R7 = R5's verified-best hot kernel, with the repack keyed BY CLUSTER-SLOT:
//   pcv[c*100+v] = {data[clusts[c,v],0], [1], [2], [4]}   (3.2 MB in d_ws)
// The repack pass absorbs the random voxel gather ONCE. The hot pass then:
//   * 2-hop chain only: edge_index (broadcast) -> pcv (streaming)
//   * pcv reads are SEQUENTIAL: consecutive points read consecutive 16 B
//     rows -> a wave covers a contiguous 256 B run per hop-2 instruction
//     (vs 16 random cache lines in R5) -> near-100% L1 hit.
//   * table stays 3.2 MB (L2-resident per XCD), unlike R6's 12.8 MB blowup
//     whose 64 B/point reads caused the 113 us regression.
// Stores stay NONTEMPORAL: 409.6 MB stream must not evict pcv from L2.

#define TOTAL_QUADS (N_EDGE * 2 * CLUST_SIZE * 4)   // 25,600,000
#define HALF_QUADS  (TOTAL_QUADS / 2)               // 12,800,000
#define BLOCK       256
#define GRID_MAIN   (HALF_QUADS / BLOCK)            // 50,000

#define N_CV        (N_CLUST * CLUST_SIZE)          // 200,000
#define GRID_RP     ((N_CV + BLOCK - 1) / BLOCK)    // 782

typedef float f32x4 __attribute__((ext_vector_type(4)));

// ---------- pass 1: pcv[cv] = packed data row of clusts[cv] ----------
__global__ __launch_bounds__(BLOCK) void repack_cv_kernel(
    const float* __restrict__ data,        // [N_VOX, 5]
    const int*   __restrict__ clusts,      // [N_CV]
    f32x4*       __restrict__ pcv)         // [N_CV]
{
    const unsigned cv = blockIdx.x * BLOCK + threadIdx.x;
    if (cv < (unsigned)N_CV) {
        const int vox = clusts[cv];                  // coalesced
        const float* dr = data + (size_t)vox * 5;    // random 20 B row
        f32x4 r = { dr[0], dr[1], dr[2], dr[4] };
        pcv[cv] = r;                                 // coalesced, cached
    }
}

// ---------- pass 2: hot writer (R5 structure, 2-hop chain) ----------
__global__ __launch_bounds__(BLOCK) void edge_enc_kernel(
    const f32x4* __restrict__ pcv,         // [N_CV]
    const int*   __restrict__ edge_index,  // [2, N_EDGE]
    const float* __restrict__ W,           // [5, 16]
    float*       __restrict__ out)         // [N_EDGE*200, 16]
{
    __shared__ float Ws[5 * N_FEAT];   // 80 floats
    if (threadIdx.x < 5 * N_FEAT) {
        Ws[threadIdx.x] = W[threadIdx.x];
    }
    __syncthreads();

    const unsigned t = blockIdx.x * BLOCK + threadIdx.x;    // 0 .. 12.8M-1

    // Both quads share fb since HALF_QUADS % 4 == 0.
    const unsigned fb    = t & 3u;
    const unsigned fbase = fb * 4u;

    float w0[4], w1[4], w2[4], w3[4], w4[4];
#pragma unroll
    for (int q = 0; q < 4; ++q) {
        w0[q] = Ws[0 * N_FEAT + fbase + q];
        w1[q] = Ws[1 * N_FEAT + fbase + q];
        w2[q] = Ws[2 * N_FEAT + fbase + q];
        w3[q] = Ws[3 * N_FEAT + fbase + q];
        w4[q] = Ws[4 * N_FEAT + fbase + q];
    }

    // ---- two independent 2-hop chains ----
    const unsigned p0 = t >> 2;
    const unsigned p1 = (t + (unsigned)HALF_QUADS) >> 2;

    const unsigned e0 = p0 / 200u;                 // magic-mul
    const unsigned e1 = p1 / 200u;
    const unsigned j0 = p0 - e0 * 200u;
    const unsigned j1 = p1 - e1 * 200u;
    const unsigned s0 = (j0 >= 100u) ? 1u : 0u;
    const unsigned s1 = (j1 >= 100u) ? 1u : 0u;
    const unsigned v0 = j0 - s0 * 100u;
    const unsigned v1 = j1 - s1 * 100u;

    const int c0 = edge_index[s0 * N_EDGE + e0];   // broadcast over 200 pts
    const int c1 = edge_index[s1 * N_EDGE + e1];

    // sequential per edge-side: consecutive points -> consecutive 16 B rows
    const f32x4 ra = pcv[(size_t)c0 * CLUST_SIZE + v0];
    const f32x4 rb = pcv[(size_t)c1 * CLUST_SIZE + v1];

    const float a3 = (float)e0;   // batch-id column := edge id
    const float b3 = (float)e1;

    float ra4[4], rb4[4];
#pragma unroll
    for (int q = 0; q < 4; ++q) {
        float va = fmaf(ra.x, w0[q], fmaf(ra.y, w1[q], fmaf(ra.z, w2[q],
                   fmaf(a3, w3[q], ra.w * w4[q]))));
        float vb = fmaf(rb.x, w0[q], fmaf(rb.y, w1[q], fmaf(rb.z, w2[q],
                   fmaf(b3, w3[q], rb.w * w4[q]))));
        ra4[q] = fmaxf(va, 0.0f);
        rb4[q] = fmaxf(vb, 0.0f);
    }

    f32x4 ova = { ra4[0], ra4[1], ra4[2], ra4[3] };
    f32x4 ovb = { rb4[0], rb4[1], rb4[2], rb4[3] };
    __builtin_nontemporal_store(ova,
        reinterpret_cast<f32x4*>(out + (size_t)p0 * N_FEAT + fbase));
    __builtin_nontemporal_store(ovb,
        reinterpret_cast<f32x4*>(out + (size_t)p1 * N_FEAT + fbase));
}

// ---------- fallback: direct 3-hop gather (R2 structure) ----------
__global__ __launch_bounds__(BLOCK) void edge_enc_direct_kernel(
    const float* __restrict__ data,
    const int*   __restrict__ clusts,
    const int*   __restrict__ edge_index,
    const float* __restrict__ W,
    float*       __restrict__ out)
{
    __shared__ float Ws[5 * N_FEAT];
    if (threadIdx.x < 5 * N_FEAT) Ws[threadIdx.x] = W[threadIdx.x];
    __syncthreads();

    const unsigned t = blockIdx.x * BLOCK + threadIdx.x;
    const unsigned fb    = t & 3u;
    const unsigned fbase = fb * 4u;

    float w0[4], w1[4], w2[4], w3[4], w4[4];
#pragma unroll
    for (int q = 0; q < 4; ++q) {
        w0[q] = Ws[0 * N_FEAT + fbase + q];
        w1[q] = Ws[1 * N_FEAT + fbase + q];
        w2[q] = Ws[2 * N_FEAT + fbase + q];
        w3[q] = Ws[3 * N_FEAT + fbase + q];
        w4[q] = Ws[4 * N_FEAT + fbase + q];
    }

    const unsigned p0 = t >> 2;
    const unsigned p1 = (t + (unsigned)HALF_QUADS) >> 2;
    const unsigned e0 = p0 / 200u, e1 = p1 / 200u;
    const unsigned j0 = p0 - e0 * 200u, j1 = p1 - e1 * 200u;
    const unsigned s0 = (j0 >= 100u) ? 1u : 0u, s1 = (j1 >= 100u) ? 1u : 0u;
    const unsigned v0 = j0 - s0 * 100u, v1 = j1 - s1 * 100u;

    const int c0 = edge_index[s0 * N_EDGE + e0];
    const int c1 = edge_index[s1 * N_EDGE + e1];
    const int vox0 = clusts[c0 * CLUST_SIZE + (int)v0];
    const int vox1 = clusts[c1 * CLUST_SIZE + (int)v1];

    const float* dr0 = data + (size_t)vox0 * 5;
    const float* dr1 = data + (size_t)vox1 * 5;
    const float a0 = dr0[0], a1 = dr0[1], a2 = dr0[2], a4 = dr0[4];
    const float b0 = dr1[0], b1 = dr1[1], b2 = dr1[2], b4 = dr1[4];
    const float a3 = (float)e0, b3 = (float)e1;

    f32x4 ova, ovb;
#pragma unroll
    for (int q = 0; q < 4; ++q) {
        float va = fmaf(a0, w0[q], fmaf(a1, w1[q], fmaf(a2, w2[q],
                   fmaf(a3, w3[q], a4 * w4[q]))));
        float vb = fmaf(b0, w0[q], fmaf(b1, w1[q], fmaf(b2, w2[q],
                   fmaf(b3, w3[q], b4 * w4[q]))));
        ova[q] = fmaxf(va, 0.0f);
        ovb[q] = fmaxf(vb, 0.0f);
    }
    __builtin_nontemporal_store(ova,
        reinterpret_cast<f32x4*>(out + (size_t)p0 * N_FEAT + fbase));
    __builtin_nontemporal_store(ovb,
        reinterpret_cast<f32x4*>(out + (size_t)p1 * N_FEAT + fbase));
}

extern "C" void kernel_launch(void* const* d_in, const int* in_sizes, int n_in,
                              void* d_out, int out_size, void* d_ws, size_t ws_size,
                              hipStream_t stream) {
    const float* data       = (const float*)d_in[0];
    const int*   clusts     = (const int*)d_in[1];
    const int*   edge_index = (const int*)d_in[2];
    const float* W          = (const float*)d_in[3];
    float*       out        = (float*)d_out;

    const size_t pcv_bytes = (size_t)N_CV * sizeof(f32x4);   // 3.2 MB
    if (ws_size >= pcv_bytes) {
        f32x4* pcv = (f32x4*)d_ws;
        repack_cv_kernel<<<GRID_RP, BLOCK, 0, stream>>>(data, clusts, pcv);
        edge_enc_kernel<<<GRID_MAIN, BLOCK, 0, stream>>>(pcv, edge_index, W, out);
    } else {
        edge_enc_direct_kernel<<<GRID_MAIN, BLOCK, 0, stream>>>(
            data, clusts, edge_index, W, out);
    }
}